// Round 1
// baseline (155.847 us; speedup 1.0000x reference)
//
#include <hip/hip_runtime.h>

// HQQ 4-bit dequant + linear (Llama-7B up-proj, decode: 8 tokens)
// OUT=11008, IN=4096, GS=64, G=704512, OC=172 (=G/IN; OUT=64*OC)
// W_q: [32, G] int32 (one packed byte per word: hi nibble -> row r=rq,
//      lo nibble -> row r=rq+32 of the [64, G] unpacked tensor)
// W_r[o, i] = ((nib - zero[g]) * scale[g]) with r=o/172, oc=o%172, g=oc*4096+i
// out[b, o] = sum_i x[b,i] * W_r[o,i] + bias[o]

#define OUT_ 11008
#define IN_ 4096
#define G_ 704512
#define OC_ 172

__global__ __launch_bounds__(256, 4)
void hqq_gemv(const int* __restrict__ Wq, const float* __restrict__ scale,
              const float* __restrict__ zero, const float* __restrict__ x,
              const float* __restrict__ bias, float* __restrict__ out) {
    const int lane = threadIdx.x;            // 0..63 : K-slice
    const int ty   = threadIdx.y;            // 0..3  : row sub-group
    const int oc   = blockIdx.y;             // 0..171
    const int rq0  = blockIdx.x * 8 + ty * 2; // this thread: packed rows rq0, rq0+1

    // acc[rr*2+0][b] = hi-nibble row of rq0+rr; acc[rr*2+1][b] = lo-nibble row
    float acc[4][8];
#pragma unroll
    for (int r = 0; r < 4; ++r)
#pragma unroll
        for (int b = 0; b < 8; ++b) acc[r][b] = 0.f;

    const long gbase = (long)oc * IN_;
    const int* __restrict__ wqA = Wq + (long)rq0 * G_ + gbase;
    const int* __restrict__ wqB = Wq + (long)(rq0 + 1) * G_ + gbase;
    const float* __restrict__ sp = scale + gbase;
    const float* __restrict__ zp = zero + gbase;

    for (int k0 = 0; k0 < IN_; k0 += 256) {
        const int i = k0 + lane * 4;
        const float4 s4 = *(const float4*)(sp + i);
        const float4 z4 = *(const float4*)(zp + i);
        float4 xv[8];
#pragma unroll
        for (int b = 0; b < 8; ++b)
            xv[b] = *(const float4*)(x + b * IN_ + i);

#pragma unroll
        for (int rr = 0; rr < 2; ++rr) {
            const int4 q4 = *(const int4*)((rr ? wqB : wqA) + i);
            const int   qs[4] = {q4.x, q4.y, q4.z, q4.w};
            const float ss[4] = {s4.x, s4.y, s4.z, s4.w};
            const float zz[4] = {z4.x, z4.y, z4.z, z4.w};
            float wh[4], wl[4];
#pragma unroll
            for (int j = 0; j < 4; ++j) {
                wh[j] = ((float)((qs[j] >> 4) & 0xF) - zz[j]) * ss[j];
                wl[j] = ((float)(qs[j] & 0xF) - zz[j]) * ss[j];
            }
#pragma unroll
            for (int b = 0; b < 8; ++b) {
                const float4 xb = xv[b];
                float ah = acc[rr * 2 + 0][b];
                float al = acc[rr * 2 + 1][b];
                ah = fmaf(xb.x, wh[0], ah);
                ah = fmaf(xb.y, wh[1], ah);
                ah = fmaf(xb.z, wh[2], ah);
                ah = fmaf(xb.w, wh[3], ah);
                al = fmaf(xb.x, wl[0], al);
                al = fmaf(xb.y, wl[1], al);
                al = fmaf(xb.z, wl[2], al);
                al = fmaf(xb.w, wl[3], al);
                acc[rr * 2 + 0][b] = ah;
                acc[rr * 2 + 1][b] = al;
            }
        }
    }

    // reduce each accumulator across the 64 lanes (K-slices)
#pragma unroll
    for (int r = 0; r < 4; ++r)
#pragma unroll
        for (int b = 0; b < 8; ++b) {
            float v = acc[r][b];
#pragma unroll
            for (int off = 32; off > 0; off >>= 1)
                v += __shfl_down(v, off, 64);
            acc[r][b] = v;
        }

    if (lane == 0) {
#pragma unroll
        for (int rr = 0; rr < 2; ++rr) {
            const int rq = rq0 + rr;
            const int o_hi = rq * OC_ + oc;
            const int o_lo = (rq + 32) * OC_ + oc;
            const float bh = bias[o_hi];
            const float bl = bias[o_lo];
#pragma unroll
            for (int b = 0; b < 8; ++b) {
                out[b * OUT_ + o_hi] = acc[rr * 2 + 0][b] + bh;
                out[b * OUT_ + o_lo] = acc[rr * 2 + 1][b] + bl;
            }
        }
    }
}

extern "C" void kernel_launch(void* const* d_in, const int* in_sizes, int n_in,
                              void* d_out, int out_size, void* d_ws, size_t ws_size,
                              hipStream_t stream) {
    const int*   Wq    = (const int*)d_in[0];    // [32, 704512] int32
    const float* scale = (const float*)d_in[1];  // [1, 704512]
    const float* zero  = (const float*)d_in[2];  // [1, 704512]
    const float* x     = (const float*)d_in[3];  // [8, 1, 4096]
    const float* bias  = (const float*)d_in[4];  // [11008]
    float* out = (float*)d_out;                  // [8, 1, 11008]

    dim3 grid(4, OC_);      // x: rq-group (8 packed rows each), y: oc
    dim3 block(64, 4);      // 64 lanes along K, 4 row sub-groups
    hqq_gemv<<<grid, block, 0, stream>>>(Wq, scale, zero, x, bias, out);
}